// Round 7
// baseline (327.765 us; speedup 1.0000x reference)
//
#include <hip/hip_runtime.h>
#include <hip/hip_bf16.h>

#define B_ 128
#define E_ 300
#define C_ 5
#define NODES 2047

typedef __attribute__((ext_vector_type(8))) short short8;
typedef __attribute__((ext_vector_type(4))) float f32x4;
typedef __hip_bfloat16 bf16;

__device__ __forceinline__ short f2bs(float v) {
  bf16 b = (bf16)v;
  return *reinterpret_cast<short*>(&b);
}

__device__ __forceinline__ short8 pack_relu(f32x4 v0, f32x4 v1) {
  short8 s;
#pragma unroll
  for (int j = 0; j < 4; j++) s[j] = f2bs(fmaxf(v0[j], 0.f));
#pragma unroll
  for (int j = 0; j < 4; j++) s[4 + j] = f2bs(fmaxf(v1[j], 0.f));
  return s;
}

// LDS out-tile addressing: row stride 312 elems, NO skew (312*2B = 624B,
// 624 mod 128 = 112 -> proj reads 2-way, frag-store reads 4-way; row data
// (304) fits stride (312) with no overlap — r6's skew overflowed the stride).
#define HSROW(base, r) ((base) + (r) * 312)

// proj fragment mask: cols 304..319 don't exist in the 304-wide tile;
// Ppf is zero there, so zero-substitution is exact.
#define PROJ_A(rowptr, ks, k0)                               \
  ((ks) == 9 && half >= 2 ? (short8){0, 0, 0, 0, 0, 0, 0, 0} \
                          : *(const short8*)((rowptr) + (k0)))

// ---------------------------------------------------------------------------
// Prep: fragment-major weights.
//  Wfrag chunks idx=(wnt*19+ks)*64+l (24320); Pqf (2432); Ppf (640).
//  chunk value[j]: row = 16*wnt+(l&15); k = 32*ks+8*(l>>4)+j (pair-k)
// ---------------------------------------------------------------------------
__global__ __launch_bounds__(256) void prep_k(const float* __restrict__ Ww,
                                              const float* __restrict__ Pw,
                                              bf16* __restrict__ Wf,
                                              bf16* __restrict__ Pqf,
                                              bf16* __restrict__ Ppf) {
  int idx = blockIdx.x * 256 + threadIdx.x;
  if (idx < 20 * 19 * 64) {
    int wnt = idx / 1216, rem = idx % 1216;
    int ks = rem >> 6, l = rem & 63;
    int n = wnt * 16 + (l & 15);
    int k0 = ks * 32 + (l >> 4) * 8;
    short8 v;
#pragma unroll
    for (int j = 0; j < 8; j++) {
      int k = k0 + j;
      float x = 0.f;
      if (n < E_) {
        if (k < E_) x = Ww[n * 600 + k];
        else if (k >= 304 && k < 604) x = Ww[n * 600 + k - 4];
      }
      v[j] = f2bs(x);
    }
    *(short8*)(Wf + (size_t)idx * 8) = v;
  }
  if (idx < 2 * 19 * 64) {
    int p = idx / 1216, rem = idx % 1216;
    int ks = rem >> 6, l = rem & 63;
    int q = l & 15;
    int k0 = ks * 32 + (l >> 4) * 8;
    short8 v;
#pragma unroll
    for (int j = 0; j < 8; j++) {
      int e = k0 + j - 304 * p;
      float x = (q < C_ && e >= 0 && e < E_) ? Pw[q * E_ + e] : 0.f;
      v[j] = f2bs(x);
    }
    *(short8*)(Pqf + (size_t)idx * 8) = v;
  }
  if (idx < 10 * 64) {
    int ks = idx >> 6, l = idx & 63;
    int q = l & 15;
    int k0 = ks * 32 + (l >> 4) * 8;
    short8 v;
#pragma unroll
    for (int j = 0; j < 8; j++) {
      int e = k0 + j;
      float x = (q < C_ && e < E_) ? Pw[q * E_ + e] : 0.f;
      v[j] = f2bs(x);
    }
    *(short8*)(Ppf + (size_t)idx * 8) = v;
  }
}

// ---------------------------------------------------------------------------
// Fused level 1: BM=64 out rows (=128 leaves), grid 1024, 4 waves.
// Gather emb f32 rows -> relu/bf16 -> LDS (long coalesced segments, stride
// 616, no skew: 2-way on frag reads), then K-loop with A via ds_read_b128
// and B/Pq coalesced fragment-major global loads. No main-loop barriers.
// ---------------------------------------------------------------------------
__global__ __launch_bounds__(256, 2) void fused_l1_k(
    const int* __restrict__ wid, const float* __restrict__ emb,
    const bf16* __restrict__ Wf, const float* __restrict__ Wb,
    const bf16* __restrict__ Pqf, const bf16* __restrict__ Ppf,
    const float* __restrict__ Pb, bf16* __restrict__ h1f,
    float* __restrict__ out) {
  __shared__ short ldsA[64 * 616 + 64];
  int tid = threadIdx.x;
  int m0 = blockIdx.x * 64;

#pragma unroll 2
  for (int it = 0; it < 19; ++it) {
    int i = it * 256 + tid;
    int r = i / 76, c2 = i % 76;
    int par = c2 >= 38 ? 1 : 0;
    int c = c2 - 38 * par;
    int word = wid[2 * (m0 + r) + par];
    const float* src = emb + (size_t)word * E_ + c * 8;
    f32x4 v0 = *(const f32x4*)src;
    f32x4 v1 = (c == 37) ? (f32x4){0.f, 0.f, 0.f, 0.f}
                         : *(const f32x4*)(src + 4);
    *(short8*)&ldsA[r * 616 + par * 304 + c * 8] = pack_relu(v0, v1);
  }
  __syncthreads();

  int w = tid >> 6, l = tid & 63, q = l & 15, half = l >> 4;
  int ab0 = (0 * 16 + q) * 616;
  int ab1 = (1 * 16 + q) * 616;
  int ab2 = (2 * 16 + q) * 616;
  int ab3 = (3 * 16 + q) * 616;

  f32x4 acc[4][5];
#pragma unroll
  for (int rt = 0; rt < 4; rt++)
#pragma unroll
    for (int nt = 0; nt < 5; nt++) acc[rt][nt] = (f32x4){0.f, 0.f, 0.f, 0.f};
  f32x4 pacc0 = (f32x4){0.f, 0.f, 0.f, 0.f};
  f32x4 pacc1 = (f32x4){0.f, 0.f, 0.f, 0.f};

#pragma unroll 2
  for (int ks = 0; ks < 19; ks++) {
    int k0 = ks * 32 + half * 8;
    short8 a0 = *(const short8*)&ldsA[ab0 + k0];
    short8 a1 = *(const short8*)&ldsA[ab1 + k0];
    short8 a2 = *(const short8*)&ldsA[ab2 + k0];
    short8 a3 = *(const short8*)&ldsA[ab3 + k0];
    short8 al = w == 0 ? a0 : (w == 1 ? a1 : (w == 2 ? a2 : a3));
    short8 pq0 = *(const short8*)(Pqf + ((size_t)(0 * 19 + ks) * 64 + l) * 8);
    short8 pq1 = *(const short8*)(Pqf + ((size_t)(1 * 19 + ks) * 64 + l) * 8);
    pacc0 = __builtin_amdgcn_mfma_f32_16x16x32_bf16(al, pq0, pacc0, 0, 0, 0);
    pacc1 = __builtin_amdgcn_mfma_f32_16x16x32_bf16(al, pq1, pacc1, 0, 0, 0);
#pragma unroll
    for (int nt = 0; nt < 5; nt++) {
      short8 b = *(const short8*)(Wf +
          ((size_t)((5 * w + nt) * 19 + ks) * 64 + l) * 8);
      acc[0][nt] =
          __builtin_amdgcn_mfma_f32_16x16x32_bf16(a0, b, acc[0][nt], 0, 0, 0);
      acc[1][nt] =
          __builtin_amdgcn_mfma_f32_16x16x32_bf16(a1, b, acc[1][nt], 0, 0, 0);
      acc[2][nt] =
          __builtin_amdgcn_mfma_f32_16x16x32_bf16(a2, b, acc[2][nt], 0, 0, 0);
      acc[3][nt] =
          __builtin_amdgcn_mfma_f32_16x16x32_bf16(a3, b, acc[3][nt], 0, 0, 0);
    }
  }
  __syncthreads();  // done reading A-tile; reuse region as out-tile

#pragma unroll
  for (int nt = 0; nt < 5; nt++) {
    int n = w * 80 + nt * 16 + q;
    float wb = (n < E_) ? Wb[n] : 0.f;
    if (n < 304) {
#pragma unroll
      for (int rt = 0; rt < 4; rt++)
#pragma unroll
        for (int j = 0; j < 4; j++) {
          int rl = rt * 16 + half * 4 + j;
          HSROW(ldsA, rl)[n] = f2bs(fmaxf(acc[rt][nt][j] + wb, 0.f));
        }
    }
  }
  if (q < C_) {
    float pb = Pb[q];
#pragma unroll
    for (int j = 0; j < 4; j++) {
      int row = m0 + w * 16 + half * 4 + j;
      int leaf0 = 2 * row, leaf1 = 2 * row + 1;
      out[((size_t)(leaf0 >> 10) * NODES + (leaf0 & 1023)) * C_ + q] =
          pacc0[j] + pb;
      out[((size_t)(leaf1 >> 10) * NODES + (leaf1 & 1023)) * C_ + q] =
          pacc1[j] + pb;
    }
  }
  __syncthreads();

  // frag-store h1 (consumer = level-2 fragments): 2 g-tiles per block
  for (int i = tid; i < 2 * 19 * 64; i += 256) {
    int gl = i / 1216, rem = i % 1216;
    int ks = rem >> 6, ll = rem & 63;
    int qq = ll & 15, hh = ll >> 4;
    int k0 = ks * 32 + hh * 8;
    int sel = k0 >= 304 ? 1 : 0;
    int e = k0 - 304 * sel;
    int lr = 2 * (gl * 16 + qq) + sel;
    short8 v = *(const short8*)&HSROW(ldsA, lr)[e];
    *(short8*)(h1f + (((size_t)((m0 >> 5) + gl) * 19 + ks) * 64 + ll) * 8) = v;
  }
  // L1 projection: wave w rows [16w, 16w+16)
  f32x4 pc = (f32x4){0.f, 0.f, 0.f, 0.f};
#pragma unroll
  for (int ks = 0; ks < 10; ks++) {
    int k0 = ks * 32 + half * 8;
    short8 a = PROJ_A(HSROW(ldsA, 16 * w + q), ks, k0);
    short8 b = *(const short8*)(Ppf + ((size_t)ks * 64 + l) * 8);
    pc = __builtin_amdgcn_mfma_f32_16x16x32_bf16(a, b, pc, 0, 0, 0);
  }
  if (q < C_) {
    float pb = Pb[q];
#pragma unroll
    for (int j = 0; j < 4; j++) {
      int m = m0 + w * 16 + half * 4 + j;
      out[((size_t)(m >> 9) * NODES + 1024 + (m & 511)) * C_ + q] = pc[j] + pb;
    }
  }
}

// ---------------------------------------------------------------------------
// Combine levels 2..5: A and B fully coalesced fragment-major global loads,
// no LDS / no barriers in the main loop. BM = 16*RT out rows, 4 waves.
// ---------------------------------------------------------------------------
template <int RT>
__global__ __launch_bounds__(256, RT == 4 ? 3 : 4) void combine_k(
    const bf16* __restrict__ hin_f, const bf16* __restrict__ Wf,
    const float* __restrict__ Wb, const bf16* __restrict__ Ppf,
    const float* __restrict__ Pb, bf16* __restrict__ hout_f,
    float* __restrict__ out, int node_off, int nshift) {
  __shared__ short hsO[RT * 16 * 312 + 64];
  int tid = threadIdx.x;
  int w = tid >> 6, l = tid & 63, q = l & 15, half = l >> 4;
  int m0 = blockIdx.x * (RT * 16);
  int g0 = m0 >> 4;

  f32x4 acc[RT][5];
#pragma unroll
  for (int rt = 0; rt < RT; rt++)
#pragma unroll
    for (int nt = 0; nt < 5; nt++) acc[rt][nt] = (f32x4){0.f, 0.f, 0.f, 0.f};

#pragma unroll 2
  for (int ks = 0; ks < 19; ks++) {
    short8 a[RT];
#pragma unroll
    for (int rt = 0; rt < RT; rt++)
      a[rt] = *(const short8*)(hin_f +
          (((size_t)(g0 + rt) * 19 + ks) * 64 + l) * 8);
#pragma unroll
    for (int nt = 0; nt < 5; nt++) {
      short8 b = *(const short8*)(Wf +
          ((size_t)((5 * w + nt) * 19 + ks) * 64 + l) * 8);
#pragma unroll
      for (int rt = 0; rt < RT; rt++)
        acc[rt][nt] = __builtin_amdgcn_mfma_f32_16x16x32_bf16(
            a[rt], b, acc[rt][nt], 0, 0, 0);
    }
  }

#pragma unroll
  for (int nt = 0; nt < 5; nt++) {
    int n = w * 80 + nt * 16 + q;
    float wb = (n < E_) ? Wb[n] : 0.f;
    if (n < 304) {
#pragma unroll
      for (int rt = 0; rt < RT; rt++)
#pragma unroll
        for (int j = 0; j < 4; j++) {
          int rl = rt * 16 + half * 4 + j;
          HSROW(hsO, rl)[n] = f2bs(fmaxf(acc[rt][nt][j] + wb, 0.f));
        }
    }
  }
  __syncthreads();

  for (int i = tid; i < (RT / 2) * 1216; i += 256) {
    int gl = i / 1216, rem = i % 1216;
    int ks = rem >> 6, ll = rem & 63;
    int qq = ll & 15, hh = ll >> 4;
    int k0 = ks * 32 + hh * 8;
    int sel = k0 >= 304 ? 1 : 0;
    int e = k0 - 304 * sel;
    int lr = 2 * (gl * 16 + qq) + sel;
    short8 v = *(const short8*)&HSROW(hsO, lr)[e];
    *(short8*)(hout_f +
               (((size_t)((m0 >> 5) + gl) * 19 + ks) * 64 + ll) * 8) = v;
  }
  if (w < RT) {
    f32x4 pacc = (f32x4){0.f, 0.f, 0.f, 0.f};
#pragma unroll
    for (int ks = 0; ks < 10; ks++) {
      int k0 = ks * 32 + half * 8;
      short8 a = PROJ_A(HSROW(hsO, 16 * w + q), ks, k0);
      short8 b = *(const short8*)(Ppf + ((size_t)ks * 64 + l) * 8);
      pacc = __builtin_amdgcn_mfma_f32_16x16x32_bf16(a, b, pacc, 0, 0, 0);
    }
    if (q < C_) {
      float pb = Pb[q];
#pragma unroll
      for (int j = 0; j < 4; j++) {
        size_t m = m0 + w * 16 + half * 4 + j;
        size_t b_ = m >> nshift;
        size_t n = m & (((size_t)1 << nshift) - 1);
        out[((size_t)b_ * NODES + node_off + n) * C_ + q] = pacc[j] + pb;
      }
    }
  }
}

// ---------------------------------------------------------------------------
// Tail: levels 6..10, one tree per block. Level-6 A read coalesced from
// h5 fragments (g = tree); levels 7..10 ping-pong in LDS.
// ---------------------------------------------------------------------------
__global__ __launch_bounds__(256, 4) void tail_k(
    const bf16* __restrict__ h5f, const bf16* __restrict__ Wf,
    const float* __restrict__ Wb, const bf16* __restrict__ Ppf,
    const float* __restrict__ Pb, float* __restrict__ out) {
  __shared__ short bufs[2][16 * 312 + 64];
  int tid = threadIdx.x, b = blockIdx.x;
  int w = tid >> 6, l = tid & 63, q = l & 15, half = l >> 4;

  int p = 0, off = 2016, Mo = 16;
  for (int lev = 0; lev < 5; lev++) {
    f32x4 acc[5];
#pragma unroll
    for (int t = 0; t < 5; t++) acc[t] = (f32x4){0.f, 0.f, 0.f, 0.f};
    for (int ks = 0; ks < 19; ks++) {
      short8 a;
      if (lev == 0) {
        a = *(const short8*)(h5f + (((size_t)b * 19 + ks) * 64 + l) * 8);
      } else {
        int k0 = ks * 32 + half * 8;
        int sel = k0 >= 304 ? 1 : 0;
        int e = k0 - 304 * sel;
        int rr = 2 * q + sel;
        rr = rr > 15 ? 15 : rr;  // clamp; garbage rows masked at store
        a = *(const short8*)&HSROW(bufs[p], rr)[e];
      }
#pragma unroll
      for (int t = 0; t < 5; t++) {
        short8 bf = *(const short8*)(Wf +
            ((size_t)((w + 4 * t) * 19 + ks) * 64 + l) * 8);
        acc[t] =
            __builtin_amdgcn_mfma_f32_16x16x32_bf16(a, bf, acc[t], 0, 0, 0);
      }
    }
    __syncthreads();
#pragma unroll
    for (int t = 0; t < 5; t++) {
      int n = (w + 4 * t) * 16 + q;
      float wb = (n < E_) ? Wb[n] : 0.f;
      if (n < 304) {
#pragma unroll
        for (int j = 0; j < 4; j++) {
          int r = half * 4 + j;
          HSROW(bufs[p ^ 1], r)[n] = f2bs(fmaxf(acc[t][j] + wb, 0.f));
        }
      }
    }
    __syncthreads();
    if (w == 0) {
      f32x4 pc = (f32x4){0.f, 0.f, 0.f, 0.f};
#pragma unroll
      for (int ks = 0; ks < 10; ks++) {
        int k0 = ks * 32 + half * 8;
        short8 a = PROJ_A(HSROW(bufs[p ^ 1], q), ks, k0);
        short8 bf = *(const short8*)(Ppf + ((size_t)ks * 64 + l) * 8);
        pc = __builtin_amdgcn_mfma_f32_16x16x32_bf16(a, bf, pc, 0, 0, 0);
      }
      if (q < C_) {
        float pb = Pb[q];
#pragma unroll
        for (int j = 0; j < 4; j++) {
          int r = half * 4 + j;
          if (r < Mo) out[((size_t)b * NODES + off + r) * C_ + q] = pc[j] + pb;
        }
      }
    }
    p ^= 1;
    off += Mo;
    Mo >>= 1;
  }
}

// ---------------------------------------------------------------------------
extern "C" void kernel_launch(void* const* d_in, const int* in_sizes, int n_in,
                              void* d_out, int out_size, void* d_ws,
                              size_t ws_size, hipStream_t stream) {
  const int* wid = (const int*)d_in[0];
  const float* emb = (const float*)d_in[1];
  const float* Ww = (const float*)d_in[2];
  const float* Wb = (const float*)d_in[3];
  const float* Pw = (const float*)d_in[4];
  const float* Pb = (const float*)d_in[5];
  float* out = (float*)d_out;

  bf16* hA = (bf16*)d_ws;                     // h1f, h3f, h5f
  bf16* hB = hA + (size_t)B_ * 512 * 304;     // h2f, h4f
  bf16* Wf = hB + (size_t)B_ * 256 * 304;
  bf16* Pqf = Wf + (size_t)20 * 19 * 512;
  bf16* Ppf = Pqf + (size_t)2 * 19 * 512;

  prep_k<<<95, 256, 0, stream>>>(Ww, Pw, Wf, Pqf, Ppf);
  fused_l1_k<<<1024, 256, 0, stream>>>(wid, emb, Wf, Wb, Pqf, Ppf, Pb, hA, out);
  combine_k<4><<<512, 256, 0, stream>>>(hA, Wf, Wb, Ppf, Pb, hB, out, 1536, 8);
  combine_k<4><<<256, 256, 0, stream>>>(hB, Wf, Wb, Ppf, Pb, hA, out, 1792, 7);
  combine_k<2><<<256, 256, 0, stream>>>(hA, Wf, Wb, Ppf, Pb, hB, out, 1920, 6);
  combine_k<2><<<128, 256, 0, stream>>>(hB, Wf, Wb, Ppf, Pb, hA, out, 1984, 5);
  tail_k<<<B_, 256, 0, stream>>>(hA, Wf, Wb, Ppf, Pb, out);
}

// Round 8
// 209.365 us; speedup vs baseline: 1.5655x; 1.5655x over previous
//
#include <hip/hip_runtime.h>
#include <hip/hip_bf16.h>

#define B_ 128
#define E_ 300
#define C_ 5
#define NODES 2047

typedef __attribute__((ext_vector_type(8))) short short8;
typedef __attribute__((ext_vector_type(4))) float f32x4;
typedef __hip_bfloat16 bf16;

__device__ __forceinline__ short f2bs(float v) {
  bf16 b = (bf16)v;
  return *reinterpret_cast<short*>(&b);
}

__device__ __forceinline__ short8 pack_relu(f32x4 v0, f32x4 v1) {
  short8 s;
#pragma unroll
  for (int j = 0; j < 4; j++) s[j] = f2bs(fmaxf(v0[j], 0.f));
#pragma unroll
  for (int j = 0; j < 4; j++) s[4 + j] = f2bs(fmaxf(v1[j], 0.f));
  return s;
}

// LDS out-tile: row stride 312 elems, no skew (proj reads 2-way aliased;
// row data 304 < 312 stride, no overlap).
#define HSROW(base, r) ((base) + (r) * 312)

// proj fragment mask: cols 304..319 don't exist in the 304-wide tile;
// Ppf is zero there, so zero-substitution is exact.
#define PROJ_A(rowptr, ks, k0)                               \
  ((ks) == 9 && half >= 2 ? (short8){0, 0, 0, 0, 0, 0, 0, 0} \
                          : *(const short8*)((rowptr) + (k0)))

// ---------------------------------------------------------------------------
// Prep: fragment-major weights.
//  Wfrag chunks idx=(wnt*19+ks)*64+l (24320); Pqf (2432); Ppf (640).
//  chunk value[j]: row = 16*wnt+(l&15); k = 32*ks+8*(l>>4)+j (pair-k)
// ---------------------------------------------------------------------------
__global__ __launch_bounds__(256) void prep_k(const float* __restrict__ Ww,
                                              const float* __restrict__ Pw,
                                              bf16* __restrict__ Wf,
                                              bf16* __restrict__ Pqf,
                                              bf16* __restrict__ Ppf) {
  int idx = blockIdx.x * 256 + threadIdx.x;
  if (idx < 20 * 19 * 64) {
    int wnt = idx / 1216, rem = idx % 1216;
    int ks = rem >> 6, l = rem & 63;
    int n = wnt * 16 + (l & 15);
    int k0 = ks * 32 + (l >> 4) * 8;
    short8 v;
#pragma unroll
    for (int j = 0; j < 8; j++) {
      int k = k0 + j;
      float x = 0.f;
      if (n < E_) {
        if (k < E_) x = Ww[n * 600 + k];
        else if (k >= 304 && k < 604) x = Ww[n * 600 + k - 4];
      }
      v[j] = f2bs(x);
    }
    *(short8*)(Wf + (size_t)idx * 8) = v;
  }
  if (idx < 2 * 19 * 64) {
    int p = idx / 1216, rem = idx % 1216;
    int ks = rem >> 6, l = rem & 63;
    int q = l & 15;
    int k0 = ks * 32 + (l >> 4) * 8;
    short8 v;
#pragma unroll
    for (int j = 0; j < 8; j++) {
      int e = k0 + j - 304 * p;
      float x = (q < C_ && e >= 0 && e < E_) ? Pw[q * E_ + e] : 0.f;
      v[j] = f2bs(x);
    }
    *(short8*)(Pqf + (size_t)idx * 8) = v;
  }
  if (idx < 10 * 64) {
    int ks = idx >> 6, l = idx & 63;
    int q = l & 15;
    int k0 = ks * 32 + (l >> 4) * 8;
    short8 v;
#pragma unroll
    for (int j = 0; j < 8; j++) {
      int e = k0 + j;
      float x = (q < C_ && e < E_) ? Pw[q * E_ + e] : 0.f;
      v[j] = f2bs(x);
    }
    *(short8*)(Ppf + (size_t)idx * 8) = v;
  }
}

// ---------------------------------------------------------------------------
// Fused level 1: BM=64 out rows (=128 leaves), grid 1024, 4 waves.
// Gather emb f32 rows -> relu/bf16 -> LDS (long coalesced segments, stride
// 616), then K-loop with A via ds_read_b128 and B/Pq coalesced
// fragment-major global loads. No main-loop barriers.
// ---------------------------------------------------------------------------
__global__ __launch_bounds__(256, 2) void fused_l1_k(
    const int* __restrict__ wid, const float* __restrict__ emb,
    const bf16* __restrict__ Wf, const float* __restrict__ Wb,
    const bf16* __restrict__ Pqf, const bf16* __restrict__ Ppf,
    const float* __restrict__ Pb, bf16* __restrict__ h1f,
    float* __restrict__ out) {
  __shared__ short ldsA[64 * 616 + 64];
  int tid = threadIdx.x;
  int m0 = blockIdx.x * 64;

#pragma unroll 2
  for (int it = 0; it < 19; ++it) {
    int i = it * 256 + tid;
    int r = i / 76, c2 = i % 76;
    int par = c2 >= 38 ? 1 : 0;
    int c = c2 - 38 * par;
    int word = wid[2 * (m0 + r) + par];
    const float* src = emb + (size_t)word * E_ + c * 8;
    f32x4 v0 = *(const f32x4*)src;
    f32x4 v1 = (c == 37) ? (f32x4){0.f, 0.f, 0.f, 0.f}
                         : *(const f32x4*)(src + 4);
    *(short8*)&ldsA[r * 616 + par * 304 + c * 8] = pack_relu(v0, v1);
  }
  __syncthreads();

  int w = tid >> 6, l = tid & 63, q = l & 15, half = l >> 4;
  int ab0 = (0 * 16 + q) * 616;
  int ab1 = (1 * 16 + q) * 616;
  int ab2 = (2 * 16 + q) * 616;
  int ab3 = (3 * 16 + q) * 616;

  f32x4 acc[4][5];
#pragma unroll
  for (int rt = 0; rt < 4; rt++)
#pragma unroll
    for (int nt = 0; nt < 5; nt++) acc[rt][nt] = (f32x4){0.f, 0.f, 0.f, 0.f};
  f32x4 pacc0 = (f32x4){0.f, 0.f, 0.f, 0.f};
  f32x4 pacc1 = (f32x4){0.f, 0.f, 0.f, 0.f};

#pragma unroll 2
  for (int ks = 0; ks < 19; ks++) {
    int k0 = ks * 32 + half * 8;
    short8 a0 = *(const short8*)&ldsA[ab0 + k0];
    short8 a1 = *(const short8*)&ldsA[ab1 + k0];
    short8 a2 = *(const short8*)&ldsA[ab2 + k0];
    short8 a3 = *(const short8*)&ldsA[ab3 + k0];
    short8 al = w == 0 ? a0 : (w == 1 ? a1 : (w == 2 ? a2 : a3));
    short8 pq0 = *(const short8*)(Pqf + ((size_t)(0 * 19 + ks) * 64 + l) * 8);
    short8 pq1 = *(const short8*)(Pqf + ((size_t)(1 * 19 + ks) * 64 + l) * 8);
    pacc0 = __builtin_amdgcn_mfma_f32_16x16x32_bf16(al, pq0, pacc0, 0, 0, 0);
    pacc1 = __builtin_amdgcn_mfma_f32_16x16x32_bf16(al, pq1, pacc1, 0, 0, 0);
#pragma unroll
    for (int nt = 0; nt < 5; nt++) {
      short8 b = *(const short8*)(Wf +
          ((size_t)((5 * w + nt) * 19 + ks) * 64 + l) * 8);
      acc[0][nt] =
          __builtin_amdgcn_mfma_f32_16x16x32_bf16(a0, b, acc[0][nt], 0, 0, 0);
      acc[1][nt] =
          __builtin_amdgcn_mfma_f32_16x16x32_bf16(a1, b, acc[1][nt], 0, 0, 0);
      acc[2][nt] =
          __builtin_amdgcn_mfma_f32_16x16x32_bf16(a2, b, acc[2][nt], 0, 0, 0);
      acc[3][nt] =
          __builtin_amdgcn_mfma_f32_16x16x32_bf16(a3, b, acc[3][nt], 0, 0, 0);
    }
  }
  __syncthreads();  // done reading A-tile; reuse region as out-tile

#pragma unroll
  for (int nt = 0; nt < 5; nt++) {
    int n = w * 80 + nt * 16 + q;
    float wb = (n < E_) ? Wb[n] : 0.f;
    if (n < 304) {
#pragma unroll
      for (int rt = 0; rt < 4; rt++)
#pragma unroll
        for (int j = 0; j < 4; j++) {
          int rl = rt * 16 + half * 4 + j;
          HSROW(ldsA, rl)[n] = f2bs(fmaxf(acc[rt][nt][j] + wb, 0.f));
        }
    }
  }
  if (q < C_) {
    float pb = Pb[q];
#pragma unroll
    for (int j = 0; j < 4; j++) {
      int row = m0 + w * 16 + half * 4 + j;
      int leaf0 = 2 * row, leaf1 = 2 * row + 1;
      out[((size_t)(leaf0 >> 10) * NODES + (leaf0 & 1023)) * C_ + q] =
          pacc0[j] + pb;
      out[((size_t)(leaf1 >> 10) * NODES + (leaf1 & 1023)) * C_ + q] =
          pacc1[j] + pb;
    }
  }
  __syncthreads();

  // frag-store h1 (consumer = level-2 fragments): 2 g-tiles per block
  for (int i = tid; i < 2 * 19 * 64; i += 256) {
    int gl = i / 1216, rem = i % 1216;
    int ks = rem >> 6, ll = rem & 63;
    int qq = ll & 15, hh = ll >> 4;
    int k0 = ks * 32 + hh * 8;
    int sel = k0 >= 304 ? 1 : 0;
    int e = k0 - 304 * sel;
    int lr = 2 * (gl * 16 + qq) + sel;
    short8 v = *(const short8*)&HSROW(ldsA, lr)[e];
    *(short8*)(h1f + (((size_t)((m0 >> 5) + gl) * 19 + ks) * 64 + ll) * 8) = v;
  }
  // L1 projection: wave w rows [16w, 16w+16)
  f32x4 pc = (f32x4){0.f, 0.f, 0.f, 0.f};
#pragma unroll
  for (int ks = 0; ks < 10; ks++) {
    int k0 = ks * 32 + half * 8;
    short8 a = PROJ_A(HSROW(ldsA, 16 * w + q), ks, k0);
    short8 b = *(const short8*)(Ppf + ((size_t)ks * 64 + l) * 8);
    pc = __builtin_amdgcn_mfma_f32_16x16x32_bf16(a, b, pc, 0, 0, 0);
  }
  if (q < C_) {
    float pb = Pb[q];
#pragma unroll
    for (int j = 0; j < 4; j++) {
      int m = m0 + w * 16 + half * 4 + j;
      out[((size_t)(m >> 9) * NODES + 1024 + (m & 511)) * C_ + q] = pc[j] + pb;
    }
  }
}

// ---------------------------------------------------------------------------
// Combine (levels 2..10): A and B fully coalesced fragment-major global
// loads, no LDS / no barriers in the main loop. BM = 16*RT out rows, 4 waves.
// ---------------------------------------------------------------------------
template <int RT>
__global__ __launch_bounds__(256, RT == 4 ? 3 : 4) void combine_k(
    const bf16* __restrict__ hin_f, const bf16* __restrict__ Wf,
    const float* __restrict__ Wb, const bf16* __restrict__ Ppf,
    const float* __restrict__ Pb, bf16* __restrict__ hout_f,
    float* __restrict__ out, int node_off, int nshift) {
  __shared__ short hsO[RT * 16 * 312 + 64];
  int tid = threadIdx.x;
  int w = tid >> 6, l = tid & 63, q = l & 15, half = l >> 4;
  int m0 = blockIdx.x * (RT * 16);
  int g0 = m0 >> 4;

  f32x4 acc[RT][5];
#pragma unroll
  for (int rt = 0; rt < RT; rt++)
#pragma unroll
    for (int nt = 0; nt < 5; nt++) acc[rt][nt] = (f32x4){0.f, 0.f, 0.f, 0.f};

#pragma unroll 2
  for (int ks = 0; ks < 19; ks++) {
    short8 a[RT];
#pragma unroll
    for (int rt = 0; rt < RT; rt++)
      a[rt] = *(const short8*)(hin_f +
          (((size_t)(g0 + rt) * 19 + ks) * 64 + l) * 8);
#pragma unroll
    for (int nt = 0; nt < 5; nt++) {
      short8 b = *(const short8*)(Wf +
          ((size_t)((5 * w + nt) * 19 + ks) * 64 + l) * 8);
#pragma unroll
      for (int rt = 0; rt < RT; rt++)
        acc[rt][nt] = __builtin_amdgcn_mfma_f32_16x16x32_bf16(
            a[rt], b, acc[rt][nt], 0, 0, 0);
    }
  }

#pragma unroll
  for (int nt = 0; nt < 5; nt++) {
    int n = w * 80 + nt * 16 + q;
    float wb = (n < E_) ? Wb[n] : 0.f;
    if (n < 304) {
#pragma unroll
      for (int rt = 0; rt < RT; rt++)
#pragma unroll
        for (int j = 0; j < 4; j++) {
          int rl = rt * 16 + half * 4 + j;
          HSROW(hsO, rl)[n] = f2bs(fmaxf(acc[rt][nt][j] + wb, 0.f));
        }
    }
  }
  __syncthreads();

  for (int i = tid; i < (RT / 2) * 1216; i += 256) {
    int gl = i / 1216, rem = i % 1216;
    int ks = rem >> 6, ll = rem & 63;
    int qq = ll & 15, hh = ll >> 4;
    int k0 = ks * 32 + hh * 8;
    int sel = k0 >= 304 ? 1 : 0;
    int e = k0 - 304 * sel;
    int lr = 2 * (gl * 16 + qq) + sel;
    short8 v = *(const short8*)&HSROW(hsO, lr)[e];
    *(short8*)(hout_f +
               (((size_t)((m0 >> 5) + gl) * 19 + ks) * 64 + ll) * 8) = v;
  }
  if (w < RT) {
    f32x4 pacc = (f32x4){0.f, 0.f, 0.f, 0.f};
#pragma unroll
    for (int ks = 0; ks < 10; ks++) {
      int k0 = ks * 32 + half * 8;
      short8 a = PROJ_A(HSROW(hsO, 16 * w + q), ks, k0);
      short8 b = *(const short8*)(Ppf + ((size_t)ks * 64 + l) * 8);
      pacc = __builtin_amdgcn_mfma_f32_16x16x32_bf16(a, b, pacc, 0, 0, 0);
    }
    if (q < C_) {
      float pb = Pb[q];
#pragma unroll
      for (int j = 0; j < 4; j++) {
        size_t m = m0 + w * 16 + half * 4 + j;
        size_t b_ = m >> nshift;
        size_t n = m & (((size_t)1 << nshift) - 1);
        out[((size_t)b_ * NODES + node_off + n) * C_ + q] = pacc[j] + pb;
      }
    }
  }
}

// ---------------------------------------------------------------------------
extern "C" void kernel_launch(void* const* d_in, const int* in_sizes, int n_in,
                              void* d_out, int out_size, void* d_ws,
                              size_t ws_size, hipStream_t stream) {
  const int* wid = (const int*)d_in[0];
  const float* emb = (const float*)d_in[1];
  const float* Ww = (const float*)d_in[2];
  const float* Wb = (const float*)d_in[3];
  const float* Pw = (const float*)d_in[4];
  const float* Pb = (const float*)d_in[5];
  float* out = (float*)d_out;

  bf16* hA = (bf16*)d_ws;                     // h1f, h3f, h5f, h7f, h9f
  bf16* hB = hA + (size_t)B_ * 512 * 304;     // h2f, h4f, h6f, h8f, h10f
  bf16* Wf = hB + (size_t)B_ * 256 * 304;
  bf16* Pqf = Wf + (size_t)20 * 19 * 512;
  bf16* Ppf = Pqf + (size_t)2 * 19 * 512;

  prep_k<<<95, 256, 0, stream>>>(Ww, Pw, Wf, Pqf, Ppf);
  fused_l1_k<<<1024, 256, 0, stream>>>(wid, emb, Wf, Wb, Pqf, Ppf, Pb, hA, out);
  // lvl2..5: M = 32768, 16384, 8192, 4096
  combine_k<4><<<512, 256, 0, stream>>>(hA, Wf, Wb, Ppf, Pb, hB, out, 1536, 8);
  combine_k<4><<<256, 256, 0, stream>>>(hB, Wf, Wb, Ppf, Pb, hA, out, 1792, 7);
  combine_k<2><<<256, 256, 0, stream>>>(hA, Wf, Wb, Ppf, Pb, hB, out, 1920, 6);
  combine_k<2><<<128, 256, 0, stream>>>(hB, Wf, Wb, Ppf, Pb, hA, out, 1984, 5);
  // lvl6..10 (ex-tail): M = 2048, 1024, 512, 256, 128 — max M-parallelism
  combine_k<2><<<64, 256, 0, stream>>>(hA, Wf, Wb, Ppf, Pb, hB, out, 2016, 4);
  combine_k<2><<<32, 256, 0, stream>>>(hB, Wf, Wb, Ppf, Pb, hA, out, 2032, 3);
  combine_k<2><<<16, 256, 0, stream>>>(hA, Wf, Wb, Ppf, Pb, hB, out, 2040, 2);
  combine_k<2><<<8, 256, 0, stream>>>(hB, Wf, Wb, Ppf, Pb, hA, out, 2044, 1);
  combine_k<2><<<4, 256, 0, stream>>>(hA, Wf, Wb, Ppf, Pb, hB, out, 2046, 0);
}